// Round 1
// baseline (1115.909 us; speedup 1.0000x reference)
//
#include <hip/hip_runtime.h>
#include <math.h>

#define B_ 4
#define C_ 64
#define H_ 256
#define W_ 256
#define N_ 65536
#define SB 130
#define SBSQ (SB*SB)

// db3 filters. DEC_* from reference; REC_* = reversed DEC_*.
#define RL_INIT {0.3326705529509569f, 0.8068915093133388f, 0.4598775021193313f, -0.13501102001039084f, -0.08544127388224149f, 0.035226291882100656f}
#define RH_INIT {0.035226291882100656f, 0.08544127388224149f, -0.13501102001039084f, -0.4598775021193313f, 0.8068915093133388f, -0.3326705529509569f}
#define DL_INIT {0.035226291882100656f, -0.08544127388224149f, -0.13501102001039084f, 0.4598775021193313f, 0.8068915093133388f, 0.3326705529509569f}
#define DH_INIT {-0.3326705529509569f, 0.8068915093133388f, -0.4598775021193313f, -0.13501102001039084f, 0.08544127388224149f, 0.035226291882100656f}

// --------------------------------------------------------------------------
// K1: DWT2 (rows then cols, stride2, zero-pad 4) fused with depthwise 3x3 on
// each subband. One block = one (b,c) plane x 16x16 subband tile.
// dsub layout: [s][b*64+c][130][130], s in {ll,lh,hl,hh} -> weights {w1,w5,w7,w9}
// --------------------------------------------------------------------------
__global__ __launch_bounds__(256) void k_dwt_dw3(
    const float* __restrict__ x,
    const float* __restrict__ w1, const float* __restrict__ w5,
    const float* __restrict__ w7, const float* __restrict__ w9,
    float* __restrict__ dsub)
{
  const float RL[6] = RL_INIT, RH[6] = RH_INIT;
  const int tx = blockIdx.x;          // subband tile col (0..8)
  const int ty = blockIdx.y;          // subband tile row (0..8)
  const int bc = blockIdx.z;          // 0..255
  const int c  = bc & 63;
  const int hs0 = ty * 16, ws0 = tx * 16;
  const int xrow0 = 2*hs0 - 6;        // raw rows needed: [2hs0-6, 2hs0+33]
  const int xcol0 = 2*ws0 - 6;

  __shared__ float xs[40][40];
  __shared__ float tlo[40][18];
  __shared__ float thi[40][18];
  __shared__ float sub[4][18][18];

  const float* xp = x + (size_t)bc * N_;
  for (int i = threadIdx.x; i < 1600; i += 256) {
    int r = i / 40, cc = i % 40;
    int gr = xrow0 + r, gc = xcol0 + cc;
    float v = 0.f;
    if ((unsigned)gr < H_ && (unsigned)gc < W_) v = xp[gr * W_ + gc];
    xs[r][cc] = v;
  }
  __syncthreads();
  // row transform along W: raw subband cols local 0..17 (global ws0-1 .. ws0+16)
  for (int i = threadIdx.x; i < 720; i += 256) {
    int r = i / 18, wsl = i % 18;
    float lo = 0.f, hi = 0.f;
#pragma unroll
    for (int t = 0; t < 6; ++t) {
      float v = xs[r][2*wsl + t];
      lo += v * RL[t];
      hi += v * RH[t];
    }
    tlo[r][wsl] = lo; thi[r][wsl] = hi;
  }
  __syncthreads();
  // col transform along H
  for (int i = threadIdx.x; i < 324; i += 256) {
    int hsl = i / 18, wsl = i % 18;
    float ll = 0.f, lh = 0.f, hl = 0.f, hh = 0.f;
#pragma unroll
    for (int t = 0; t < 6; ++t) {
      float a = tlo[2*hsl + t][wsl];
      float b = thi[2*hsl + t][wsl];
      ll += a * RL[t]; lh += a * RH[t];
      hl += b * RL[t]; hh += b * RH[t];
    }
    sub[0][hsl][wsl] = ll; sub[1][hsl][wsl] = lh;
    sub[2][hsl][wsl] = hl; sub[3][hsl][wsl] = hh;
  }
  __syncthreads();
  // dw3 (zero-pad) + store; raw subband OOB values are already 0 via x zero-pad
  const int hsl = (threadIdx.x >> 4) + 1, wsl = (threadIdx.x & 15) + 1;
  const int hs = hs0 + hsl - 1, ws = ws0 + wsl - 1;
  if (hs < SB && ws < SB) {
    const float* wsel[4] = {w1 + c*9, w5 + c*9, w7 + c*9, w9 + c*9};
#pragma unroll
    for (int s = 0; s < 4; ++s) {
      float acc = 0.f;
#pragma unroll
      for (int dy = 0; dy < 3; ++dy)
#pragma unroll
        for (int dx = 0; dx < 3; ++dx)
          acc += sub[s][hsl + dy - 1][wsl + dx - 1] * wsel[s][dy*3 + dx];
      dsub[((size_t)s * 256 + bc) * SBSQ + hs * SB + ws] = acc;
    }
  }
}

// --------------------------------------------------------------------------
// K2: IDWT2 (H then W, lhs_dilation=2, pad=1, DEC filters) fused in LDS.
// Also accumulates nq[b*64+c] = sum q^2 (for l2norm of q rows).
// --------------------------------------------------------------------------
__global__ __launch_bounds__(256) void k_idwt(
    const float* __restrict__ dsub,
    float* __restrict__ q,
    float* __restrict__ nq)
{
  const float DL[6] = DL_INIT, DH[6] = DH_INIT;
  const int bx = blockIdx.x, by = blockIdx.y, bc = blockIdx.z;
  const int h0 = by * 32, w0 = bx * 32;
  const int j0h = h0 >> 1, j0w = w0 >> 1;

  __shared__ float ds[4][18][18];
  __shared__ float lo2[32][18];
  __shared__ float hi2[32][18];

  for (int i = threadIdx.x; i < 4*18*18; i += 256) {
    int s = i / 324, rem = i % 324, r = rem / 18, cc = rem % 18;
    ds[s][r][cc] = dsub[((size_t)s * 256 + bc) * SBSQ + (j0h + r) * SB + (j0w + cc)];
  }
  __syncthreads();
  // H pass: q-row local hl 0..31 (h0 even -> local parity == global parity)
  for (int i = threadIdx.x; i < 32*18; i += 256) {
    int hl = i / 18, wsl = i % 18;
    float lo = 0.f, hi = 0.f;
#pragma unroll
    for (int t = 0; t < 6; ++t) {
      int num = hl + t - 1;
      if ((num & 1) == 0) {
        int jl = num >> 1;                    // always in [0,18)
        lo += ds[0][jl][wsl] * DL[t] + ds[1][jl][wsl] * DH[t];
        hi += ds[2][jl][wsl] * DL[t] + ds[3][jl][wsl] * DH[t];
      }
    }
    lo2[hl][wsl] = lo; hi2[hl][wsl] = hi;
  }
  __syncthreads();
  // W pass + write q + nq partial
  float nqacc = 0.f;
  for (int i = threadIdx.x; i < 1024; i += 256) {
    int hl = i >> 5, wl = i & 31;
    float v = 0.f;
#pragma unroll
    for (int t = 0; t < 6; ++t) {
      int num = wl + t - 1;
      if ((num & 1) == 0) {
        int jl = num >> 1;
        v += lo2[hl][jl] * DL[t] + hi2[hl][jl] * DH[t];
      }
    }
    q[(size_t)bc * N_ + (h0 + hl) * W_ + (w0 + wl)] = v;
    nqacc += v * v;
  }
#pragma unroll
  for (int off = 32; off > 0; off >>= 1) nqacc += __shfl_down(nqacc, off, 64);
  __shared__ float red4[4];
  if ((threadIdx.x & 63) == 0) red4[threadIdx.x >> 6] = nqacc;
  __syncthreads();
  if (threadIdx.x == 0)
    atomicAdd(&nq[bc], red4[0] + red4[1] + red4[2] + red4[3]);
}

// --------------------------------------------------------------------------
// K3: conv1x1 half (64 out-channels): out[b,co,n] = sum_ci W[co_off+co,ci] x[b,ci,n]
// 64px x 64co tile per block; LDS-staged X and transposed W (padded stride 68).
// --------------------------------------------------------------------------
__global__ __launch_bounds__(256) void k_conv1x1(
    const float* __restrict__ x,
    const float* __restrict__ wq,
    const int co_off,
    float* __restrict__ out)
{
  const int b = blockIdx.y;
  const int n0 = blockIdx.x * 64;
  __shared__ float Xs[64][64];
  __shared__ float Wt[64][68];        // Wt[ci][co], padded stride (16B-aligned)

  for (int i = threadIdx.x; i < 4096; i += 256) {
    int ci = i >> 6, px = i & 63;
    Xs[ci][px] = x[((size_t)b * 64 + ci) * N_ + n0 + px];
  }
  for (int i = threadIdx.x; i < 4096; i += 256) {
    int co = i >> 6, ci = i & 63;
    Wt[ci][co] = wq[(co_off + co) * 64 + ci];
  }
  __syncthreads();

  const int co0 = (threadIdx.x >> 4) * 4;
  const int nn0 = (threadIdx.x & 15) * 4;
  float acc[4][4] = {};
#pragma unroll
  for (int ci = 0; ci < 64; ++ci) {
    float4 xv = *(const float4*)&Xs[ci][nn0];
    float4 wv = *(const float4*)&Wt[ci][co0];
    acc[0][0] += wv.x*xv.x; acc[0][1] += wv.x*xv.y; acc[0][2] += wv.x*xv.z; acc[0][3] += wv.x*xv.w;
    acc[1][0] += wv.y*xv.x; acc[1][1] += wv.y*xv.y; acc[1][2] += wv.y*xv.z; acc[1][3] += wv.y*xv.w;
    acc[2][0] += wv.z*xv.x; acc[2][1] += wv.z*xv.y; acc[2][2] += wv.z*xv.z; acc[2][3] += wv.z*xv.w;
    acc[3][0] += wv.w*xv.x; acc[3][1] += wv.w*xv.y; acc[3][2] += wv.w*xv.z; acc[3][3] += wv.w*xv.w;
  }
#pragma unroll
  for (int i2 = 0; i2 < 4; ++i2) {
    float4 o4 = make_float4(acc[i2][0], acc[i2][1], acc[i2][2], acc[i2][3]);
    *(float4*)&out[((size_t)b * 64 + co0 + i2) * N_ + n0 + nn0] = o4;
  }
}

// --------------------------------------------------------------------------
// K4k: dw3 on k-half (on the fly) + reduction S[b,hd,c,d] += q[c]*k[d],
// nk[b,hd,d] += k^2.  Block = (b, head, 32x32 tile); 256 thr = 8 d x 32 lanes.
// --------------------------------------------------------------------------
__global__ __launch_bounds__(256) void k_kred(
    const float* __restrict__ kpre,
    const float* __restrict__ q,
    const float* __restrict__ wc,     // w_qkv_conv, rows [0,64)
    float* __restrict__ S,
    float* __restrict__ nk)
{
  const int b = blockIdx.z, hd = blockIdx.y, tile = blockIdx.x;
  const int h0 = (tile >> 3) * 32, w0 = (tile & 7) * 32;
  const int d = threadIdx.x >> 5, lane = threadIdx.x & 31;
  const int ck = hd * 8 + d;
  const float* kp = kpre + ((size_t)b * 64 + ck) * N_;
  const float* qp = q + ((size_t)b * 64 + hd * 8) * N_;
  float wk[9];
#pragma unroll
  for (int i = 0; i < 9; ++i) wk[i] = wc[ck * 9 + i];

  float sacc[8] = {};
  float nkacc = 0.f;
  for (int r = 0; r < 32; ++r) {
    const int hh = h0 + r, ww = w0 + lane;
    float kv = 0.f;
#pragma unroll
    for (int dy = -1; dy <= 1; ++dy) {
      int h2 = hh + dy;
      if ((unsigned)h2 >= H_) continue;
#pragma unroll
      for (int dx = -1; dx <= 1; ++dx) {
        int w2 = ww + dx;
        if ((unsigned)w2 >= W_) continue;
        kv += kp[h2 * W_ + w2] * wk[(dy+1)*3 + (dx+1)];
      }
    }
    nkacc += kv * kv;
    const size_t npix = (size_t)hh * W_ + ww;
#pragma unroll
    for (int cc = 0; cc < 8; ++cc)
      sacc[cc] += qp[(size_t)cc * N_ + npix] * kv;
  }
#pragma unroll
  for (int m = 16; m >= 1; m >>= 1) {
#pragma unroll
    for (int cc = 0; cc < 8; ++cc) sacc[cc] += __shfl_xor(sacc[cc], m, 64);
    nkacc += __shfl_xor(nkacc, m, 64);
  }
  if (lane == 0) {
#pragma unroll
    for (int cc = 0; cc < 8; ++cc)
      atomicAdd(&S[(((size_t)b * 8 + hd) * 8 + cc) * 8 + d], sacc[cc]);
    atomicAdd(&nk[((size_t)b * 8 + hd) * 8 + d], nkacc);
  }
}

// --------------------------------------------------------------------------
// K4v: dw3 on v-half -> v.  One block per (b, cv, h); threads = w.
// --------------------------------------------------------------------------
__global__ __launch_bounds__(256) void k_dw3v(
    const float* __restrict__ vpre,
    const float* __restrict__ wc,     // rows [64,128)
    float* __restrict__ v)
{
  const int h = blockIdx.x, cv = blockIdx.y, b = blockIdx.z;
  const int w = threadIdx.x;
  const float* vp = vpre + ((size_t)b * 64 + cv) * N_;
  float wk[9];
#pragma unroll
  for (int i = 0; i < 9; ++i) wk[i] = wc[(64 + cv) * 9 + i];
  float acc = 0.f;
#pragma unroll
  for (int dy = -1; dy <= 1; ++dy) {
    int h2 = h + dy;
    if ((unsigned)h2 >= H_) continue;
#pragma unroll
    for (int dx = -1; dx <= 1; ++dx) {
      int w2 = w + dx;
      if ((unsigned)w2 >= W_) continue;
      acc += vp[h2 * W_ + w2] * wk[(dy+1)*3 + (dx+1)];
    }
  }
  v[((size_t)b * 64 + cv) * N_ + h * W_ + w] = acc;
}

// --------------------------------------------------------------------------
// K5: attention matrices.  A1 = softmax_d(S1/(|q_c||k1_d|)*temp),
// A2 = softmax_d(S2/|k2_d|*temp)  (q NOT normalized in attn2, per reference).
// One thread per (b,h,c) row.
// --------------------------------------------------------------------------
__global__ __launch_bounds__(256) void k_attn(
    const float* __restrict__ S1, const float* __restrict__ S2,
    const float* __restrict__ nq, const float* __restrict__ nk1,
    const float* __restrict__ nk2, const float* __restrict__ temp,
    float* __restrict__ A1, float* __restrict__ A2)
{
  const int t = threadIdx.x;
  const int b = t >> 6, h = (t >> 3) & 7, c = t & 7;
  const float tp = temp[h];
  const float qn = fmaxf(sqrtf(nq[t]), 1e-12f);
  const size_t rowoff = (((size_t)b * 8 + h) * 8 + c) * 8;
  const size_t noff = ((size_t)b * 8 + h) * 8;

  float l[8];
#pragma unroll
  for (int d = 0; d < 8; ++d)
    l[d] = S1[rowoff + d] / (qn * fmaxf(sqrtf(nk1[noff + d]), 1e-12f)) * tp;
  float m = l[0];
#pragma unroll
  for (int d = 1; d < 8; ++d) m = fmaxf(m, l[d]);
  float sum = 0.f;
#pragma unroll
  for (int d = 0; d < 8; ++d) { l[d] = expf(l[d] - m); sum += l[d]; }
#pragma unroll
  for (int d = 0; d < 8; ++d) A1[rowoff + d] = l[d] / sum;

#pragma unroll
  for (int d = 0; d < 8; ++d)
    l[d] = S2[rowoff + d] / fmaxf(sqrtf(nk2[noff + d]), 1e-12f) * tp;
  m = l[0];
#pragma unroll
  for (int d = 1; d < 8; ++d) m = fmaxf(m, l[d]);
  sum = 0.f;
#pragma unroll
  for (int d = 0; d < 8; ++d) { l[d] = expf(l[d] - m); sum += l[d]; }
#pragma unroll
  for (int d = 0; d < 8; ++d) A2[rowoff + d] = l[d] / sum;
}

// --------------------------------------------------------------------------
// K6: out = w_proj @ ((A1 v_r) * (A2 v_d)), per 64-pixel tile.
// --------------------------------------------------------------------------
__global__ __launch_bounds__(256) void k_out(
    const float* __restrict__ vr, const float* __restrict__ vd,
    const float* __restrict__ A1, const float* __restrict__ A2,
    const float* __restrict__ P,
    float* __restrict__ out)
{
  const int b = blockIdx.y;
  const int n0 = blockIdx.x * 64;
  __shared__ float vrs[64][64];
  __shared__ float vds[64][64];
  __shared__ float us[64][64];
  __shared__ float a1s[512], a2s[512];

  for (int i = threadIdx.x; i < 4096; i += 256) {
    int cc = i >> 6, px = i & 63;
    vrs[cc][px] = vr[((size_t)b * 64 + cc) * N_ + n0 + px];
    vds[cc][px] = vd[((size_t)b * 64 + cc) * N_ + n0 + px];
  }
  for (int i = threadIdx.x; i < 512; i += 256) {
    a1s[i] = A1[b * 512 + i];
    a2s[i] = A2[b * 512 + i];
  }
  __syncthreads();
  for (int i = threadIdx.x; i < 4096; i += 256) {
    int cc = i >> 6, px = i & 63;
    int hh = cc >> 3;
    float s = 0.f, tt = 0.f;
#pragma unroll
    for (int dd = 0; dd < 8; ++dd) {
      s  += a1s[cc * 8 + dd] * vrs[hh * 8 + dd][px];
      tt += a2s[cc * 8 + dd] * vds[hh * 8 + dd][px];
    }
    us[cc][px] = s * tt;
  }
  __syncthreads();
  const int px = threadIdx.x & 63;
  const int og = threadIdx.x >> 6;       // 4 groups of 16 output channels
  float acc[16] = {};
  for (int cc4 = 0; cc4 < 64; cc4 += 4) {
    float u0 = us[cc4 + 0][px], u1 = us[cc4 + 1][px];
    float u2 = us[cc4 + 2][px], u3 = us[cc4 + 3][px];
#pragma unroll
    for (int i = 0; i < 16; ++i) {
      float4 pv = *(const float4*)&P[(og * 16 + i) * 64 + cc4];
      acc[i] += pv.x * u0 + pv.y * u1 + pv.z * u2 + pv.w * u3;
    }
  }
#pragma unroll
  for (int i = 0; i < 16; ++i)
    out[((size_t)b * 64 + og * 16 + i) * N_ + n0 + px] = acc[i];
}

// --------------------------------------------------------------------------
extern "C" void kernel_launch(void* const* d_in, const int* in_sizes, int n_in,
                              void* d_out, int out_size, void* d_ws, size_t ws_size,
                              hipStream_t stream) {
  (void)in_sizes; (void)n_in; (void)out_size;
  const float* rgb  = (const float*)d_in[0];
  const float* dep  = (const float*)d_in[1];
  const float* temp = (const float*)d_in[2];
  const float* wqr  = (const float*)d_in[3];
  const float* wqd  = (const float*)d_in[4];
  const float* wqc  = (const float*)d_in[5];
  const float* w1   = (const float*)d_in[6];
  const float* w5   = (const float*)d_in[7];
  const float* w7   = (const float*)d_in[8];
  const float* w9   = (const float*)d_in[9];
  const float* wp   = (const float*)d_in[10];
  float* out = (float*)d_out;

  // ws layout (bytes):
  //   A @ 0         : q (67.1MB), later reused as v_d (q dead after depth k-reduce)
  //   B @ 67108864  : v_r (67.1MB)
  //   C @ 134217728 : dsub (69.2MB) -> k_pre/v_pre scratch (67.1MB), sequential reuse
  //   D @ 203440128 : S1,S2,nq,nk1,nk2 (zeroed) + A1,A2
  const size_t WS_NEEDED = 203475968;
  if (ws_size < WS_NEEDED) return;    // clean no-op -> visible validation failure

  char* ws = (char*)d_ws;
  float* q   = (float*)(ws + 0);
  float* v_d = q;
  float* v_r = (float*)(ws + 67108864);
  float* big = (float*)(ws + 134217728);
  char* redb = ws + 203440128;
  float* S1  = (float*)(redb);
  float* S2  = (float*)(redb + 8192);
  float* nq  = (float*)(redb + 16384);
  float* nk1 = (float*)(redb + 17408);
  float* nk2 = (float*)(redb + 18432);
  float* A1  = (float*)(redb + 19456);
  float* A2  = (float*)(redb + 27648);

  hipMemsetAsync(redb, 0, 19456, stream);

  // q = mfe(rgb): DWT+dw3 -> dsub, then IDWT -> q (+nq)
  k_dwt_dw3<<<dim3(9, 9, 256), 256, 0, stream>>>(rgb, w1, w5, w7, w9, big);
  k_idwt<<<dim3(8, 8, 256), 256, 0, stream>>>(big, q, nq);

  // rgb stream: k-half -> reduce(S1,nk1); v-half -> dw3 -> v_r
  k_conv1x1<<<dim3(1024, 4), 256, 0, stream>>>(rgb, wqr, 0, big);
  k_kred<<<dim3(64, 8, 4), 256, 0, stream>>>(big, q, wqc, S1, nk1);
  k_conv1x1<<<dim3(1024, 4), 256, 0, stream>>>(rgb, wqr, 64, big);
  k_dw3v<<<dim3(256, 64, 4), 256, 0, stream>>>(big, wqc, v_r);

  // depth stream: k-half -> reduce(S2,nk2); v-half -> dw3 -> v_d (over q)
  k_conv1x1<<<dim3(1024, 4), 256, 0, stream>>>(dep, wqd, 0, big);
  k_kred<<<dim3(64, 8, 4), 256, 0, stream>>>(big, q, wqc, S2, nk2);
  k_conv1x1<<<dim3(1024, 4), 256, 0, stream>>>(dep, wqd, 64, big);
  k_dw3v<<<dim3(256, 64, 4), 256, 0, stream>>>(big, wqc, v_d);

  // tiny attention matrices, then the fused gated projection
  k_attn<<<1, 256, 0, stream>>>(S1, S2, nq, nk1, nk2, temp, A1, A2);
  k_out<<<dim3(1024, 4), 256, 0, stream>>>(v_r, v_d, A1, A2, wp, out);
}

// Round 2
// 848.421 us; speedup vs baseline: 1.3153x; 1.3153x over previous
//
#include <hip/hip_runtime.h>
#include <math.h>

#define B_ 4
#define C_ 64
#define H_ 256
#define W_ 256
#define N_ 65536
#define SB 130
#define SBSQ (SB*SB)

// db3 filters. DEC_* from reference; REC_* = reversed DEC_*.
#define RL_INIT {0.3326705529509569f, 0.8068915093133388f, 0.4598775021193313f, -0.13501102001039084f, -0.08544127388224149f, 0.035226291882100656f}
#define RH_INIT {0.035226291882100656f, 0.08544127388224149f, -0.13501102001039084f, -0.4598775021193313f, 0.8068915093133388f, -0.3326705529509569f}
#define DL_INIT {0.035226291882100656f, -0.08544127388224149f, -0.13501102001039084f, 0.4598775021193313f, 0.8068915093133388f, 0.3326705529509569f}
#define DH_INIT {-0.3326705529509569f, 0.8068915093133388f, -0.4598775021193313f, -0.13501102001039084f, 0.08544127388224149f, 0.035226291882100656f}

// --------------------------------------------------------------------------
// K1: DWT2 (rows then cols, stride2, zero-pad 4) fused with depthwise 3x3 on
// each subband. One block = one (b,c) plane x 16x16 subband tile.  (unchanged)
// --------------------------------------------------------------------------
__global__ __launch_bounds__(256) void k_dwt_dw3(
    const float* __restrict__ x,
    const float* __restrict__ w1, const float* __restrict__ w5,
    const float* __restrict__ w7, const float* __restrict__ w9,
    float* __restrict__ dsub)
{
  const float RL[6] = RL_INIT, RH[6] = RH_INIT;
  const int tx = blockIdx.x;
  const int ty = blockIdx.y;
  const int bc = blockIdx.z;
  const int c  = bc & 63;
  const int hs0 = ty * 16, ws0 = tx * 16;
  const int xrow0 = 2*hs0 - 6;
  const int xcol0 = 2*ws0 - 6;

  __shared__ float xs[40][40];
  __shared__ float tlo[40][18];
  __shared__ float thi[40][18];
  __shared__ float sub[4][18][18];

  const float* xp = x + (size_t)bc * N_;
  for (int i = threadIdx.x; i < 1600; i += 256) {
    int r = i / 40, cc = i % 40;
    int gr = xrow0 + r, gc = xcol0 + cc;
    float v = 0.f;
    if ((unsigned)gr < H_ && (unsigned)gc < W_) v = xp[gr * W_ + gc];
    xs[r][cc] = v;
  }
  __syncthreads();
  for (int i = threadIdx.x; i < 720; i += 256) {
    int r = i / 18, wsl = i % 18;
    float lo = 0.f, hi = 0.f;
#pragma unroll
    for (int t = 0; t < 6; ++t) {
      float v = xs[r][2*wsl + t];
      lo += v * RL[t];
      hi += v * RH[t];
    }
    tlo[r][wsl] = lo; thi[r][wsl] = hi;
  }
  __syncthreads();
  for (int i = threadIdx.x; i < 324; i += 256) {
    int hsl = i / 18, wsl = i % 18;
    float ll = 0.f, lh = 0.f, hl = 0.f, hh = 0.f;
#pragma unroll
    for (int t = 0; t < 6; ++t) {
      float a = tlo[2*hsl + t][wsl];
      float b = thi[2*hsl + t][wsl];
      ll += a * RL[t]; lh += a * RH[t];
      hl += b * RL[t]; hh += b * RH[t];
    }
    sub[0][hsl][wsl] = ll; sub[1][hsl][wsl] = lh;
    sub[2][hsl][wsl] = hl; sub[3][hsl][wsl] = hh;
  }
  __syncthreads();
  const int hsl = (threadIdx.x >> 4) + 1, wsl = (threadIdx.x & 15) + 1;
  const int hs = hs0 + hsl - 1, ws = ws0 + wsl - 1;
  if (hs < SB && ws < SB) {
    const float* wsel[4] = {w1 + c*9, w5 + c*9, w7 + c*9, w9 + c*9};
#pragma unroll
    for (int s = 0; s < 4; ++s) {
      float acc = 0.f;
#pragma unroll
      for (int dy = 0; dy < 3; ++dy)
#pragma unroll
        for (int dx = 0; dx < 3; ++dx)
          acc += sub[s][hsl + dy - 1][wsl + dx - 1] * wsel[s][dy*3 + dx];
      dsub[((size_t)s * 256 + bc) * SBSQ + hs * SB + ws] = acc;
    }
  }
}

// --------------------------------------------------------------------------
// K2: IDWT2 fused in LDS + nq accumulation.  (unchanged)
// --------------------------------------------------------------------------
__global__ __launch_bounds__(256) void k_idwt(
    const float* __restrict__ dsub,
    float* __restrict__ q,
    float* __restrict__ nq)
{
  const float DL[6] = DL_INIT, DH[6] = DH_INIT;
  const int bx = blockIdx.x, by = blockIdx.y, bc = blockIdx.z;
  const int h0 = by * 32, w0 = bx * 32;
  const int j0h = h0 >> 1, j0w = w0 >> 1;

  __shared__ float ds[4][18][18];
  __shared__ float lo2[32][18];
  __shared__ float hi2[32][18];

  for (int i = threadIdx.x; i < 4*18*18; i += 256) {
    int s = i / 324, rem = i % 324, r = rem / 18, cc = rem % 18;
    ds[s][r][cc] = dsub[((size_t)s * 256 + bc) * SBSQ + (j0h + r) * SB + (j0w + cc)];
  }
  __syncthreads();
  for (int i = threadIdx.x; i < 32*18; i += 256) {
    int hl = i / 18, wsl = i % 18;
    float lo = 0.f, hi = 0.f;
#pragma unroll
    for (int t = 0; t < 6; ++t) {
      int num = hl + t - 1;
      if ((num & 1) == 0) {
        int jl = num >> 1;
        lo += ds[0][jl][wsl] * DL[t] + ds[1][jl][wsl] * DH[t];
        hi += ds[2][jl][wsl] * DL[t] + ds[3][jl][wsl] * DH[t];
      }
    }
    lo2[hl][wsl] = lo; hi2[hl][wsl] = hi;
  }
  __syncthreads();
  float nqacc = 0.f;
  for (int i = threadIdx.x; i < 1024; i += 256) {
    int hl = i >> 5, wl = i & 31;
    float v = 0.f;
#pragma unroll
    for (int t = 0; t < 6; ++t) {
      int num = wl + t - 1;
      if ((num & 1) == 0) {
        int jl = num >> 1;
        v += lo2[hl][jl] * DL[t] + hi2[hl][jl] * DH[t];
      }
    }
    q[(size_t)bc * N_ + (h0 + hl) * W_ + (w0 + wl)] = v;
    nqacc += v * v;
  }
#pragma unroll
  for (int off = 32; off > 0; off >>= 1) nqacc += __shfl_down(nqacc, off, 64);
  __shared__ float red4[4];
  if ((threadIdx.x & 63) == 0) red4[threadIdx.x >> 6] = nqacc;
  __syncthreads();
  if (threadIdx.x == 0)
    atomicAdd(&nq[bc], red4[0] + red4[1] + red4[2] + red4[3]);
}

// --------------------------------------------------------------------------
// K3: conv1x1 half. 128px x 64co tile; 8 px/thread -> 32 FMA per 3 LDS b128.
// --------------------------------------------------------------------------
__global__ __launch_bounds__(256) void k_conv1x1(
    const float* __restrict__ x,
    const float* __restrict__ wq,
    const int co_off,
    float* __restrict__ out)
{
  const int b = blockIdx.y;
  const int n0 = blockIdx.x * 128;
  __shared__ float Xs[64][128];       // 32 KB
  __shared__ float Wt[64][68];        // Wt[ci][co], 16B-aligned rows

  // stage X as float4 (coalesced 16B/lane)
  for (int i = threadIdx.x; i < 2048; i += 256) {
    int ci = i >> 5, f = i & 31;
    *(float4*)&Xs[ci][f * 4] =
        *(const float4*)&x[((size_t)b * 64 + ci) * N_ + n0 + f * 4];
  }
  // stage W transposed (coalesced global reads)
  for (int i = threadIdx.x; i < 4096; i += 256) {
    int co = i >> 6, ci = i & 63;
    Wt[ci][co] = wq[(co_off + co) * 64 + ci];
  }
  __syncthreads();

  const int px_g = threadIdx.x & 15;   // 16 groups x 8 px = 128
  const int co_g = threadIdx.x >> 4;   // 16 groups x 4 co = 64
  const int p0 = px_g * 4;
  float acc[4][8] = {};
#pragma unroll 2
  for (int ci = 0; ci < 64; ++ci) {
    float4 x0 = *(const float4*)&Xs[ci][p0];
    float4 x1 = *(const float4*)&Xs[ci][64 + p0];
    float4 wv = *(const float4*)&Wt[ci][co_g * 4];
    const float wr[4] = {wv.x, wv.y, wv.z, wv.w};
    const float xr[8] = {x0.x, x0.y, x0.z, x0.w, x1.x, x1.y, x1.z, x1.w};
#pragma unroll
    for (int i = 0; i < 4; ++i)
#pragma unroll
      for (int j = 0; j < 8; ++j)
        acc[i][j] += wr[i] * xr[j];
  }
#pragma unroll
  for (int i = 0; i < 4; ++i) {
    float* op = &out[((size_t)b * 64 + co_g * 4 + i) * N_ + n0];
    *(float4*)&op[p0]      = make_float4(acc[i][0], acc[i][1], acc[i][2], acc[i][3]);
    *(float4*)&op[64 + p0] = make_float4(acc[i][4], acc[i][5], acc[i][6], acc[i][7]);
  }
}

// --------------------------------------------------------------------------
// K4k: dw3 on k-half (kpre halo tile staged in LDS) + reduction
// S[b,hd,c,d] += q[c]*k[d], nk[b,hd,d] += k^2.
// Block = (b, head, 32x32 tile); 256 thr = 8 d x 32 lanes.
// --------------------------------------------------------------------------
__global__ __launch_bounds__(256) void k_kred(
    const float* __restrict__ kpre,
    const float* __restrict__ q,
    const float* __restrict__ wc,
    float* __restrict__ S,
    float* __restrict__ nk)
{
  const int b = blockIdx.z, hd = blockIdx.y, tile = blockIdx.x;
  const int h0 = (tile >> 3) * 32, w0 = (tile & 7) * 32;
  const int d = threadIdx.x >> 5, lane = threadIdx.x & 31;
  const int ck = hd * 8 + d;

  __shared__ float ks[8][34][36];     // 39.2 KB, halo tile (zero-padded)

  // stage: rows h0-1..h0+32, cols w0-1..w0+32 for the head's 8 k-channels
  for (int i = threadIdx.x; i < 9248; i += 256) {
    int ch = i / 1156, rem = i % 1156;
    int r = rem / 34, cc = rem % 34;
    int gh = h0 - 1 + r, gw = w0 - 1 + cc;
    float v = 0.f;
    if ((unsigned)gh < H_ && (unsigned)gw < W_)
      v = kpre[((size_t)b * 64 + hd * 8 + ch) * N_ + gh * W_ + gw];
    ks[ch][r][cc] = v;
  }
  __syncthreads();

  float wk[9];
#pragma unroll
  for (int i = 0; i < 9; ++i) wk[i] = wc[ck * 9 + i];
  const float* qp = q + ((size_t)b * 64 + hd * 8) * N_;

  float sacc[8] = {};
  float nkacc = 0.f;
  for (int r = 0; r < 32; ++r) {
    float kv = 0.f;
#pragma unroll
    for (int dy = 0; dy < 3; ++dy)
#pragma unroll
      for (int dx = 0; dx < 3; ++dx)
        kv += ks[d][r + dy][lane + dx] * wk[dy * 3 + dx];
    nkacc += kv * kv;
    const size_t npix = (size_t)(h0 + r) * W_ + w0 + lane;
#pragma unroll
    for (int cc = 0; cc < 8; ++cc)
      sacc[cc] += qp[(size_t)cc * N_ + npix] * kv;
  }
#pragma unroll
  for (int m = 16; m >= 1; m >>= 1) {
#pragma unroll
    for (int cc = 0; cc < 8; ++cc) sacc[cc] += __shfl_xor(sacc[cc], m, 64);
    nkacc += __shfl_xor(nkacc, m, 64);
  }
  if (lane == 0) {
#pragma unroll
    for (int cc = 0; cc < 8; ++cc)
      atomicAdd(&S[(((size_t)b * 8 + hd) * 8 + cc) * 8 + d], sacc[cc]);
    atomicAdd(&nk[((size_t)b * 8 + hd) * 8 + d], nkacc);
  }
}

// --------------------------------------------------------------------------
// K4v: dw3 on v-half, 32x32 LDS-tiled with halo.
// --------------------------------------------------------------------------
__global__ __launch_bounds__(256) void k_dw3v(
    const float* __restrict__ vpre,
    const float* __restrict__ wc,     // rows [64,128)
    float* __restrict__ v)
{
  const int tile = blockIdx.x, cv = blockIdx.y, b = blockIdx.z;
  const int h0 = (tile >> 3) * 32, w0 = (tile & 7) * 32;
  __shared__ float vs[34][36];

  const float* vp = vpre + ((size_t)b * 64 + cv) * N_;
  for (int i = threadIdx.x; i < 1156; i += 256) {
    int r = i / 34, cc = i % 34;
    int gh = h0 - 1 + r, gw = w0 - 1 + cc;
    float val = 0.f;
    if ((unsigned)gh < H_ && (unsigned)gw < W_) val = vp[gh * W_ + gw];
    vs[r][cc] = val;
  }
  __syncthreads();

  float wk[9];
#pragma unroll
  for (int i = 0; i < 9; ++i) wk[i] = wc[(64 + cv) * 9 + i];

  for (int i = threadIdx.x; i < 1024; i += 256) {
    int r = i >> 5, cc = i & 31;
    float acc = 0.f;
#pragma unroll
    for (int dy = 0; dy < 3; ++dy)
#pragma unroll
      for (int dx = 0; dx < 3; ++dx)
        acc += vs[r + dy][cc + dx] * wk[dy * 3 + dx];
    v[((size_t)b * 64 + cv) * N_ + (h0 + r) * W_ + w0 + cc] = acc;
  }
}

// --------------------------------------------------------------------------
// K5: attention matrices (unchanged).
// --------------------------------------------------------------------------
__global__ __launch_bounds__(256) void k_attn(
    const float* __restrict__ S1, const float* __restrict__ S2,
    const float* __restrict__ nq, const float* __restrict__ nk1,
    const float* __restrict__ nk2, const float* __restrict__ temp,
    float* __restrict__ A1, float* __restrict__ A2)
{
  const int t = threadIdx.x;
  const int b = t >> 6, h = (t >> 3) & 7, c = t & 7;
  const float tp = temp[h];
  const float qn = fmaxf(sqrtf(nq[t]), 1e-12f);
  const size_t rowoff = (((size_t)b * 8 + h) * 8 + c) * 8;
  const size_t noff = ((size_t)b * 8 + h) * 8;

  float l[8];
#pragma unroll
  for (int d = 0; d < 8; ++d)
    l[d] = S1[rowoff + d] / (qn * fmaxf(sqrtf(nk1[noff + d]), 1e-12f)) * tp;
  float m = l[0];
#pragma unroll
  for (int d = 1; d < 8; ++d) m = fmaxf(m, l[d]);
  float sum = 0.f;
#pragma unroll
  for (int d = 0; d < 8; ++d) { l[d] = expf(l[d] - m); sum += l[d]; }
#pragma unroll
  for (int d = 0; d < 8; ++d) A1[rowoff + d] = l[d] / sum;

#pragma unroll
  for (int d = 0; d < 8; ++d)
    l[d] = S2[rowoff + d] / fmaxf(sqrtf(nk2[noff + d]), 1e-12f) * tp;
  m = l[0];
#pragma unroll
  for (int d = 1; d < 8; ++d) m = fmaxf(m, l[d]);
  sum = 0.f;
#pragma unroll
  for (int d = 0; d < 8; ++d) { l[d] = expf(l[d] - m); sum += l[d]; }
#pragma unroll
  for (int d = 0; d < 8; ++d) A2[rowoff + d] = l[d] / sum;
}

// --------------------------------------------------------------------------
// K6: out = w_proj @ ((A1 v_r) * (A2 v_d)).  Gating in registers (thread =
// 64-px column x 16-channel group), P staged transposed in LDS, then a
// conv1x1-style 64x64 GEMM.  LDS 37.4 KB -> 4 blocks/CU.
// --------------------------------------------------------------------------
__global__ __launch_bounds__(256) void k_out(
    const float* __restrict__ vr, const float* __restrict__ vd,
    const float* __restrict__ A1, const float* __restrict__ A2,
    const float* __restrict__ P,
    float* __restrict__ out)
{
  const int b = blockIdx.y;
  const int n0 = blockIdx.x * 64;
  __shared__ float us[64][64];        // 16 KB  gated values u[c][px]
  __shared__ float Pl[64][68];        // 17.4 KB  Pl[cc][co] = P[co][cc]
  __shared__ float a1s[512], a2s[512];

  for (int i = threadIdx.x; i < 4096; i += 256) {
    int co = i >> 6, cc = i & 63;
    Pl[cc][co] = P[co * 64 + cc];     // coalesced global read
  }
  for (int i = threadIdx.x; i < 512; i += 256) {
    a1s[i] = A1[b * 512 + i];
    a2s[i] = A2[b * 512 + i];
  }
  __syncthreads();

  // phase A: gate.  thread = (px, g); channels g*16..g*16+15 (heads 2g,2g+1)
  {
    const int px = threadIdx.x & 63;
    const int g = threadIdx.x >> 6;
    const int ch0 = g * 16;
    float vrr[16], vdd[16];
#pragma unroll
    for (int j = 0; j < 16; ++j) {
      vrr[j] = vr[((size_t)b * 64 + ch0 + j) * N_ + n0 + px];
      vdd[j] = vd[((size_t)b * 64 + ch0 + j) * N_ + n0 + px];
    }
#pragma unroll
    for (int j = 0; j < 16; ++j) {
      const int c = ch0 + j;
      const int base = (j & 8);
      float s = 0.f, t2 = 0.f;
#pragma unroll
      for (int dd = 0; dd < 8; ++dd) {
        s  += a1s[c * 8 + dd] * vrr[base + dd];
        t2 += a2s[c * 8 + dd] * vdd[base + dd];
      }
      us[c][px] = s * t2;
    }
  }
  __syncthreads();

  // phase B: out[co][px] = sum_cc P[co][cc] * u[cc][px]
  const int px_g = threadIdx.x & 15;
  const int co_g = threadIdx.x >> 4;
  const int p0 = px_g * 4;
  float acc[4][4] = {};
#pragma unroll 2
  for (int cc = 0; cc < 64; ++cc) {
    float4 uv = *(const float4*)&us[cc][p0];
    float4 pv = *(const float4*)&Pl[cc][co_g * 4];
    const float pr[4] = {pv.x, pv.y, pv.z, pv.w};
    const float ur[4] = {uv.x, uv.y, uv.z, uv.w};
#pragma unroll
    for (int i = 0; i < 4; ++i)
#pragma unroll
      for (int j = 0; j < 4; ++j)
        acc[i][j] += pr[i] * ur[j];
  }
#pragma unroll
  for (int i = 0; i < 4; ++i)
    *(float4*)&out[((size_t)b * 64 + co_g * 4 + i) * N_ + n0 + p0] =
        make_float4(acc[i][0], acc[i][1], acc[i][2], acc[i][3]);
}

// --------------------------------------------------------------------------
extern "C" void kernel_launch(void* const* d_in, const int* in_sizes, int n_in,
                              void* d_out, int out_size, void* d_ws, size_t ws_size,
                              hipStream_t stream) {
  (void)in_sizes; (void)n_in; (void)out_size;
  const float* rgb  = (const float*)d_in[0];
  const float* dep  = (const float*)d_in[1];
  const float* temp = (const float*)d_in[2];
  const float* wqr  = (const float*)d_in[3];
  const float* wqd  = (const float*)d_in[4];
  const float* wqc  = (const float*)d_in[5];
  const float* w1   = (const float*)d_in[6];
  const float* w5   = (const float*)d_in[7];
  const float* w7   = (const float*)d_in[8];
  const float* w9   = (const float*)d_in[9];
  const float* wp   = (const float*)d_in[10];
  float* out = (float*)d_out;

  const size_t WS_NEEDED = 203475968;
  if (ws_size < WS_NEEDED) return;

  char* ws = (char*)d_ws;
  float* q   = (float*)(ws + 0);
  float* v_d = q;                      // q dead after depth k-reduce
  float* v_r = (float*)(ws + 67108864);
  float* big = (float*)(ws + 134217728);
  char* redb = ws + 203440128;
  float* S1  = (float*)(redb);
  float* S2  = (float*)(redb + 8192);
  float* nq  = (float*)(redb + 16384);
  float* nk1 = (float*)(redb + 17408);
  float* nk2 = (float*)(redb + 18432);
  float* A1  = (float*)(redb + 19456);
  float* A2  = (float*)(redb + 27648);

  hipMemsetAsync(redb, 0, 19456, stream);

  k_dwt_dw3<<<dim3(9, 9, 256), 256, 0, stream>>>(rgb, w1, w5, w7, w9, big);
  k_idwt<<<dim3(8, 8, 256), 256, 0, stream>>>(big, q, nq);

  k_conv1x1<<<dim3(512, 4), 256, 0, stream>>>(rgb, wqr, 0, big);
  k_kred<<<dim3(64, 8, 4), 256, 0, stream>>>(big, q, wqc, S1, nk1);
  k_conv1x1<<<dim3(512, 4), 256, 0, stream>>>(rgb, wqr, 64, big);
  k_dw3v<<<dim3(64, 64, 4), 256, 0, stream>>>(big, wqc, v_r);

  k_conv1x1<<<dim3(512, 4), 256, 0, stream>>>(dep, wqd, 0, big);
  k_kred<<<dim3(64, 8, 4), 256, 0, stream>>>(big, q, wqc, S2, nk2);
  k_conv1x1<<<dim3(512, 4), 256, 0, stream>>>(dep, wqd, 64, big);
  k_dw3v<<<dim3(64, 64, 4), 256, 0, stream>>>(big, wqc, v_d);

  k_attn<<<1, 256, 0, stream>>>(S1, S2, nq, nk1, nk2, temp, A1, A2);
  k_out<<<dim3(1024, 4), 256, 0, stream>>>(v_r, v_d, A1, A2, wp, out);
}

// Round 5
// 763.575 us; speedup vs baseline: 1.4614x; 1.1111x over previous
//
#include <hip/hip_runtime.h>
#include <math.h>

#define B_ 4
#define C_ 64
#define H_ 256
#define W_ 256
#define N_ 65536

// db3 filters. DEC_* from reference; REC_* = reversed DEC_*.
#define RL_INIT {0.3326705529509569f, 0.8068915093133388f, 0.4598775021193313f, -0.13501102001039084f, -0.08544127388224149f, 0.035226291882100656f}
#define RH_INIT {0.035226291882100656f, 0.08544127388224149f, -0.13501102001039084f, -0.4598775021193313f, 0.8068915093133388f, -0.3326705529509569f}
#define DL_INIT {0.035226291882100656f, -0.08544127388224149f, -0.13501102001039084f, 0.4598775021193313f, 0.8068915093133388f, 0.3326705529509569f}
#define DH_INIT {-0.3326705529509569f, 0.8068915093133388f, -0.4598775021193313f, -0.13501102001039084f, 0.08544127388224149f, 0.035226291882100656f}

// --------------------------------------------------------------------------
// K_MFE: fully fused q = idwt2(dw3(dwt2(x))) for one 64x64 output tile of one
// (b,c) plane.  No dsub global round trip.  Also accumulates nq = sum q^2.
//
// Index algebra (h0 = tile row base; sub local row sj <-> global j_g = h0/2-2+sj):
//   subband row j_g <- x rows 2*j_g-4 .. 2*j_g+1  (pad=4, stride=2 correl.)
//   IDWT output row i = h0+hl needs global j = (i-(i&1))/2 + o, o=0..2,
//     coeff D[2o+1-(hl&1)]  -> local sj = (hl>>1)+2+o.
//   dt row dr stores dw3(sub) centered at sj = dr+1 (taps sub rows dr..dr+2),
//     so P4 reads dt rows (hl>>1)+1+o.  [R4 bug: taps were dr-1..dr+1]
// LDS overlays: A = xs[78][80] -> sub[4][37][38] -> lo2/hi2[64][36]
//               B = tlo/thi[78][38] -> dt[4][35][36]       (peak 48.7 KB)
// --------------------------------------------------------------------------
__global__ __launch_bounds__(256) void k_mfe(
    const float* __restrict__ x,
    const float* __restrict__ w1, const float* __restrict__ w5,
    const float* __restrict__ w7, const float* __restrict__ w9,
    float* __restrict__ q, float* __restrict__ nq)
{
  const float RL[6] = RL_INIT, RH[6] = RH_INIT;
  const float DL[6] = DL_INIT, DH[6] = DH_INIT;
  const int bc = blockIdx.z;
  const int c  = bc & 63;
  const int h0 = blockIdx.y * 64, w0 = blockIdx.x * 64;

  __shared__ float A[6240];           // 24.96 KB
  __shared__ float Bm[5928];          // 23.71 KB
  float* xs  = A;                     // [78][80]
  float* sub = A;                     // [4][37][38]  (37*38 = 1406)
  float* lo2 = A;                     // [64][36]
  float* hi2 = A + 2304;              // [64][36]
  float* tlo = Bm;                    // [78][38]
  float* thi = Bm + 2964;             // [78][38]
  float* dt  = Bm;                    // [4][35][36]  (35*36 = 1260)

  // per-channel dw3 weights (uniform across block)
  float wk[4][9];
#pragma unroll
  for (int i = 0; i < 9; ++i) {
    wk[0][i] = w1[c * 9 + i]; wk[1][i] = w5[c * 9 + i];
    wk[2][i] = w7[c * 9 + i]; wk[3][i] = w9[c * 9 + i];
  }

  // P0: stage x halo tile rows [h0-8, h0+69], cols [w0-8, w0+69], zero-pad
  {
    const float* xp = x + (size_t)bc * N_;
    const int xr0 = h0 - 8, xc0 = w0 - 8;
    for (int i = threadIdx.x; i < 78 * 39; i += 256) {
      int r = i / 39, c2 = i % 39;
      int gr = xr0 + r, gc = xc0 + c2 * 2;
      float2 v = make_float2(0.f, 0.f);
      if ((unsigned)gr < H_ && (unsigned)gc < W_)
        v = *(const float2*)&xp[gr * W_ + gc];   // gc even, W_ even -> safe
      *(float2*)&xs[r * 80 + c2 * 2] = v;
    }
  }
  __syncthreads();

  // P1: row DWT -> tlo/thi [78][37 used]
  for (int i = threadIdx.x; i < 78 * 37; i += 256) {
    int r = i / 37, sw = i % 37;
    const float* xr = &xs[r * 80 + 2 * sw];
    float lo = 0.f, hi = 0.f;
#pragma unroll
    for (int t = 0; t < 6; ++t) {
      float v = xr[t];
      lo += v * RL[t]; hi += v * RH[t];
    }
    tlo[r * 38 + sw] = lo; thi[r * 38 + sw] = hi;
  }
  __syncthreads();

  // P2: col DWT -> sub[4][37][38] (overlays xs; xs dead)
  for (int i = threadIdx.x; i < 37 * 37; i += 256) {
    int sj = i / 37, sw = i % 37;
    int base = (2 * sj) * 38 + sw;
    float ll = 0.f, lh = 0.f, hl = 0.f, hh = 0.f;
#pragma unroll
    for (int t = 0; t < 6; ++t) {
      float a = tlo[base + t * 38];
      float b = thi[base + t * 38];
      ll += a * RL[t]; lh += a * RH[t];
      hl += b * RL[t]; hh += b * RH[t];
    }
    sub[0 * 1406 + sj * 38 + sw] = ll;
    sub[1 * 1406 + sj * 38 + sw] = lh;
    sub[2 * 1406 + sj * 38 + sw] = hl;
    sub[3 * 1406 + sj * 38 + sw] = hh;
  }
  __syncthreads();

  // P3: dw3 on each subband -> dt[4][35][36], rows/cols [1,34] written.
  //     dt[dr][dc] = dw3(sub) centered at local (sj,sw) = (dr+1,dc+1);
  //     taps read sub rows dr..dr+2, cols dc..dc+2 (zero-pad is natural:
  //     sub rows/cols outside the real 130-range are exact zeros).
  for (int i = threadIdx.x; i < 34 * 34; i += 256) {
    int dr = i / 34 + 1, dc = i % 34 + 1;
#pragma unroll
    for (int s = 0; s < 4; ++s) {
      const float* sp = &sub[s * 1406 + dr * 38 + dc];   // center (dr+1,dc+1)
      float acc = 0.f;
#pragma unroll
      for (int dy = 0; dy < 3; ++dy)
#pragma unroll
        for (int dx = 0; dx < 3; ++dx)
          acc += sp[dy * 38 + dx] * wk[s][dy * 3 + dx];
      dt[s * 1260 + dr * 36 + dc] = acc;
    }
  }
  __syncthreads();

  // P4: idwt H pass -> lo2/hi2 [64][cols 1..34] (overlays sub; sub dead)
  for (int i = threadIdx.x; i < 64 * 34; i += 256) {
    int hl = i / 34, dc = i % 34 + 1;
    int idx0 = (hl >> 1) + 1;
    int po = hl & 1;                  // coeff index 2o+1-po
    float lo = 0.f, hi = 0.f;
#pragma unroll
    for (int o = 0; o < 3; ++o) {
      int rr = (idx0 + o) * 36 + dc;
      float cl = DL[2 * o + 1 - po], ch = DH[2 * o + 1 - po];
      lo += dt[0 * 1260 + rr] * cl + dt[1 * 1260 + rr] * ch;
      hi += dt[2 * 1260 + rr] * cl + dt[3 * 1260 + rr] * ch;
    }
    lo2[hl * 36 + dc] = lo; hi2[hl * 36 + dc] = hi;
  }
  __syncthreads();

  // P5: idwt W pass -> q + nq
  float nqacc = 0.f;
  for (int i = threadIdx.x; i < 4096; i += 256) {
    int hl = i >> 6, wl = i & 63;
    int ci0 = (wl >> 1) + 1;
    int po = wl & 1;
    const float* lr = &lo2[hl * 36 + ci0];
    const float* hr = &hi2[hl * 36 + ci0];
    float v = 0.f;
#pragma unroll
    for (int o = 0; o < 3; ++o)
      v += lr[o] * DL[2 * o + 1 - po] + hr[o] * DH[2 * o + 1 - po];
    q[(size_t)bc * N_ + (h0 + hl) * W_ + (w0 + wl)] = v;
    nqacc += v * v;
  }
#pragma unroll
  for (int off = 32; off > 0; off >>= 1) nqacc += __shfl_down(nqacc, off, 64);
  __shared__ float red4[4];
  if ((threadIdx.x & 63) == 0) red4[threadIdx.x >> 6] = nqacc;
  __syncthreads();
  if (threadIdx.x == 0)
    atomicAdd(&nq[bc], red4[0] + red4[1] + red4[2] + red4[3]);
}

// --------------------------------------------------------------------------
// K3: conv1x1 half. 128px x 64co tile; 8 px/thread.  (unchanged, validated)
// --------------------------------------------------------------------------
__global__ __launch_bounds__(256) void k_conv1x1(
    const float* __restrict__ x,
    const float* __restrict__ wq,
    const int co_off,
    float* __restrict__ out)
{
  const int b = blockIdx.y;
  const int n0 = blockIdx.x * 128;
  __shared__ float Xs[64][128];
  __shared__ float Wt[64][68];

  for (int i = threadIdx.x; i < 2048; i += 256) {
    int ci = i >> 5, f = i & 31;
    *(float4*)&Xs[ci][f * 4] =
        *(const float4*)&x[((size_t)b * 64 + ci) * N_ + n0 + f * 4];
  }
  for (int i = threadIdx.x; i < 4096; i += 256) {
    int co = i >> 6, ci = i & 63;
    Wt[ci][co] = wq[(co_off + co) * 64 + ci];
  }
  __syncthreads();

  const int px_g = threadIdx.x & 15;
  const int co_g = threadIdx.x >> 4;
  const int p0 = px_g * 4;
  float acc[4][8] = {};
#pragma unroll 2
  for (int ci = 0; ci < 64; ++ci) {
    float4 x0 = *(const float4*)&Xs[ci][p0];
    float4 x1 = *(const float4*)&Xs[ci][64 + p0];
    float4 wv = *(const float4*)&Wt[ci][co_g * 4];
    const float wr[4] = {wv.x, wv.y, wv.z, wv.w};
    const float xr[8] = {x0.x, x0.y, x0.z, x0.w, x1.x, x1.y, x1.z, x1.w};
#pragma unroll
    for (int i = 0; i < 4; ++i)
#pragma unroll
      for (int j = 0; j < 8; ++j)
        acc[i][j] += wr[i] * xr[j];
  }
#pragma unroll
  for (int i = 0; i < 4; ++i) {
    float* op = &out[((size_t)b * 64 + co_g * 4 + i) * N_ + n0];
    *(float4*)&op[p0]      = make_float4(acc[i][0], acc[i][1], acc[i][2], acc[i][3]);
    *(float4*)&op[64 + p0] = make_float4(acc[i][4], acc[i][5], acc[i][6], acc[i][7]);
  }
}

// --------------------------------------------------------------------------
// K4k: dw3 on k-half (LDS halo tile) + S/nk reduction.  (unchanged, validated)
// --------------------------------------------------------------------------
__global__ __launch_bounds__(256) void k_kred(
    const float* __restrict__ kpre,
    const float* __restrict__ q,
    const float* __restrict__ wc,
    float* __restrict__ S,
    float* __restrict__ nk)
{
  const int b = blockIdx.z, hd = blockIdx.y, tile = blockIdx.x;
  const int h0 = (tile >> 3) * 32, w0 = (tile & 7) * 32;
  const int d = threadIdx.x >> 5, lane = threadIdx.x & 31;
  const int ck = hd * 8 + d;

  __shared__ float ks[8][34][36];

  for (int i = threadIdx.x; i < 9248; i += 256) {
    int ch = i / 1156, rem = i % 1156;
    int r = rem / 34, cc = rem % 34;
    int gh = h0 - 1 + r, gw = w0 - 1 + cc;
    float v = 0.f;
    if ((unsigned)gh < H_ && (unsigned)gw < W_)
      v = kpre[((size_t)b * 64 + hd * 8 + ch) * N_ + gh * W_ + gw];
    ks[ch][r][cc] = v;
  }
  __syncthreads();

  float wk[9];
#pragma unroll
  for (int i = 0; i < 9; ++i) wk[i] = wc[ck * 9 + i];
  const float* qp = q + ((size_t)b * 64 + hd * 8) * N_;

  float sacc[8] = {};
  float nkacc = 0.f;
  for (int r = 0; r < 32; ++r) {
    float kv = 0.f;
#pragma unroll
    for (int dy = 0; dy < 3; ++dy)
#pragma unroll
      for (int dx = 0; dx < 3; ++dx)
        kv += ks[d][r + dy][lane + dx] * wk[dy * 3 + dx];
    nkacc += kv * kv;
    const size_t npix = (size_t)(h0 + r) * W_ + w0 + lane;
#pragma unroll
    for (int cc = 0; cc < 8; ++cc)
      sacc[cc] += qp[(size_t)cc * N_ + npix] * kv;
  }
#pragma unroll
  for (int m = 16; m >= 1; m >>= 1) {
#pragma unroll
    for (int cc = 0; cc < 8; ++cc) sacc[cc] += __shfl_xor(sacc[cc], m, 64);
    nkacc += __shfl_xor(nkacc, m, 64);
  }
  if (lane == 0) {
#pragma unroll
    for (int cc = 0; cc < 8; ++cc)
      atomicAdd(&S[(((size_t)b * 8 + hd) * 8 + cc) * 8 + d], sacc[cc]);
    atomicAdd(&nk[((size_t)b * 8 + hd) * 8 + d], nkacc);
  }
}

// --------------------------------------------------------------------------
// K4v: dw3 on v-half, 32x32 LDS-tiled with halo.  (unchanged, validated)
// --------------------------------------------------------------------------
__global__ __launch_bounds__(256) void k_dw3v(
    const float* __restrict__ vpre,
    const float* __restrict__ wc,
    float* __restrict__ v)
{
  const int tile = blockIdx.x, cv = blockIdx.y, b = blockIdx.z;
  const int h0 = (tile >> 3) * 32, w0 = (tile & 7) * 32;
  __shared__ float vs[34][36];

  const float* vp = vpre + ((size_t)b * 64 + cv) * N_;
  for (int i = threadIdx.x; i < 1156; i += 256) {
    int r = i / 34, cc = i % 34;
    int gh = h0 - 1 + r, gw = w0 - 1 + cc;
    float val = 0.f;
    if ((unsigned)gh < H_ && (unsigned)gw < W_) val = vp[gh * W_ + gw];
    vs[r][cc] = val;
  }
  __syncthreads();

  float wk[9];
#pragma unroll
  for (int i = 0; i < 9; ++i) wk[i] = wc[(64 + cv) * 9 + i];

  for (int i = threadIdx.x; i < 1024; i += 256) {
    int r = i >> 5, cc = i & 31;
    float acc = 0.f;
#pragma unroll
    for (int dy = 0; dy < 3; ++dy)
#pragma unroll
      for (int dx = 0; dx < 3; ++dx)
        acc += vs[r + dy][cc + dx] * wk[dy * 3 + dx];
    v[((size_t)b * 64 + cv) * N_ + (h0 + r) * W_ + w0 + cc] = acc;
  }
}

// --------------------------------------------------------------------------
// K6: out = w_proj @ ((A1 v_r) * (A2 v_d)), with the tiny per-b attention
// softmaxes recomputed per block (k_attn folded in; S/n* reads are L2-hot).
// --------------------------------------------------------------------------
__global__ __launch_bounds__(256) void k_out(
    const float* __restrict__ vr, const float* __restrict__ vd,
    const float* __restrict__ S1, const float* __restrict__ S2,
    const float* __restrict__ nq, const float* __restrict__ nk1,
    const float* __restrict__ nk2, const float* __restrict__ temp,
    const float* __restrict__ P,
    float* __restrict__ out)
{
  const int b = blockIdx.y;
  const int n0 = blockIdx.x * 64;
  __shared__ float us[64][64];
  __shared__ float Pl[64][68];
  __shared__ float a1s[512], a2s[512];

  for (int i = threadIdx.x; i < 4096; i += 256) {
    int co = i >> 6, cc = i & 63;
    Pl[cc][co] = P[co * 64 + cc];
  }
  // attention rows (one thread per (h,c); 8-wide softmax each)
  if (threadIdx.x < 64) {
    const int t = threadIdx.x;
    const int h = t >> 3;
    const float tp = temp[h];
    const float qn = fmaxf(sqrtf(nq[b * 64 + t]), 1e-12f);
    const size_t rowoff = ((size_t)b * 64 + t) * 8;
    const size_t noff = ((size_t)b * 8 + h) * 8;
    float l[8];
#pragma unroll
    for (int d = 0; d < 8; ++d)
      l[d] = S1[rowoff + d] / (qn * fmaxf(sqrtf(nk1[noff + d]), 1e-12f)) * tp;
    float m = l[0];
#pragma unroll
    for (int d = 1; d < 8; ++d) m = fmaxf(m, l[d]);
    float sum = 0.f;
#pragma unroll
    for (int d = 0; d < 8; ++d) { l[d] = expf(l[d] - m); sum += l[d]; }
#pragma unroll
    for (int d = 0; d < 8; ++d) a1s[t * 8 + d] = l[d] / sum;
#pragma unroll
    for (int d = 0; d < 8; ++d)
      l[d] = S2[rowoff + d] / fmaxf(sqrtf(nk2[noff + d]), 1e-12f) * tp;
    m = l[0];
#pragma unroll
    for (int d = 1; d < 8; ++d) m = fmaxf(m, l[d]);
    sum = 0.f;
#pragma unroll
    for (int d = 0; d < 8; ++d) { l[d] = expf(l[d] - m); sum += l[d]; }
#pragma unroll
    for (int d = 0; d < 8; ++d) a2s[t * 8 + d] = l[d] / sum;
  }
  __syncthreads();

  // phase A: gate in registers
  {
    const int px = threadIdx.x & 63;
    const int g = threadIdx.x >> 6;
    const int ch0 = g * 16;
    float vrr[16], vdd[16];
#pragma unroll
    for (int j = 0; j < 16; ++j) {
      vrr[j] = vr[((size_t)b * 64 + ch0 + j) * N_ + n0 + px];
      vdd[j] = vd[((size_t)b * 64 + ch0 + j) * N_ + n0 + px];
    }
#pragma unroll
    for (int j = 0; j < 16; ++j) {
      const int c = ch0 + j;
      const int base = (j & 8);
      float s = 0.f, t2 = 0.f;
#pragma unroll
      for (int dd = 0; dd < 8; ++dd) {
        s  += a1s[c * 8 + dd] * vrr[base + dd];
        t2 += a2s[c * 8 + dd] * vdd[base + dd];
      }
      us[c][px] = s * t2;
    }
  }
  __syncthreads();

  // phase B: 64x64 projection GEMM
  const int px_g = threadIdx.x & 15;
  const int co_g = threadIdx.x >> 4;
  const int p0 = px_g * 4;
  float acc[4][4] = {};
#pragma unroll 2
  for (int cc = 0; cc < 64; ++cc) {
    float4 uv = *(const float4*)&us[cc][p0];
    float4 pv = *(const float4*)&Pl[cc][co_g * 4];
    const float pr[4] = {pv.x, pv.y, pv.z, pv.w};
    const float ur[4] = {uv.x, uv.y, uv.z, uv.w};
#pragma unroll
    for (int i = 0; i < 4; ++i)
#pragma unroll
      for (int j = 0; j < 4; ++j)
        acc[i][j] += pr[i] * ur[j];
  }
#pragma unroll
  for (int i = 0; i < 4; ++i)
    *(float4*)&out[((size_t)b * 64 + co_g * 4 + i) * N_ + n0 + p0] =
        make_float4(acc[i][0], acc[i][1], acc[i][2], acc[i][3]);
}

// --------------------------------------------------------------------------
extern "C" void kernel_launch(void* const* d_in, const int* in_sizes, int n_in,
                              void* d_out, int out_size, void* d_ws, size_t ws_size,
                              hipStream_t stream) {
  (void)in_sizes; (void)n_in; (void)out_size;
  const float* rgb  = (const float*)d_in[0];
  const float* dep  = (const float*)d_in[1];
  const float* temp = (const float*)d_in[2];
  const float* wqr  = (const float*)d_in[3];
  const float* wqd  = (const float*)d_in[4];
  const float* wqc  = (const float*)d_in[5];
  const float* w1   = (const float*)d_in[6];
  const float* w5   = (const float*)d_in[7];
  const float* w7   = (const float*)d_in[8];
  const float* w9   = (const float*)d_in[9];
  const float* wp   = (const float*)d_in[10];
  float* out = (float*)d_out;

  const size_t WS_NEEDED = 203475968;
  if (ws_size < WS_NEEDED) return;

  char* ws = (char*)d_ws;
  float* q   = (float*)(ws + 0);
  float* v_d = q;                      // q dead after depth k-reduce
  float* v_r = (float*)(ws + 67108864);
  float* big = (float*)(ws + 134217728);   // conv1x1 scratch (67.1 MB)
  char* redb = ws + 203440128;
  float* S1  = (float*)(redb);
  float* S2  = (float*)(redb + 8192);
  float* nq  = (float*)(redb + 16384);
  float* nk1 = (float*)(redb + 17408);
  float* nk2 = (float*)(redb + 18432);

  hipMemsetAsync(redb, 0, 19456, stream);

  // q = mfe(rgb), fully fused
  k_mfe<<<dim3(4, 4, 256), 256, 0, stream>>>(rgb, w1, w5, w7, w9, q, nq);

  // rgb stream
  k_conv1x1<<<dim3(512, 4), 256, 0, stream>>>(rgb, wqr, 0, big);
  k_kred<<<dim3(64, 8, 4), 256, 0, stream>>>(big, q, wqc, S1, nk1);
  k_conv1x1<<<dim3(512, 4), 256, 0, stream>>>(rgb, wqr, 64, big);
  k_dw3v<<<dim3(64, 64, 4), 256, 0, stream>>>(big, wqc, v_r);

  // depth stream
  k_conv1x1<<<dim3(512, 4), 256, 0, stream>>>(dep, wqd, 0, big);
  k_kred<<<dim3(64, 8, 4), 256, 0, stream>>>(big, q, wqc, S2, nk2);
  k_conv1x1<<<dim3(512, 4), 256, 0, stream>>>(dep, wqd, 64, big);
  k_dw3v<<<dim3(64, 64, 4), 256, 0, stream>>>(big, wqc, v_d);

  // gated projection with fused attention softmaxes
  k_out<<<dim3(1024, 4), 256, 0, stream>>>(v_r, v_d, S1, S2, nq, nk1, nk2,
                                           temp, wp, out);
}

// Round 6
// 711.424 us; speedup vs baseline: 1.5686x; 1.0733x over previous
//
#include <hip/hip_runtime.h>
#include <math.h>

#define B_ 4
#define C_ 64
#define H_ 256
#define W_ 256
#define N_ 65536

// db3 filters. DEC_* from reference; REC_* = reversed DEC_*.
#define RL_INIT {0.3326705529509569f, 0.8068915093133388f, 0.4598775021193313f, -0.13501102001039084f, -0.08544127388224149f, 0.035226291882100656f}
#define RH_INIT {0.035226291882100656f, 0.08544127388224149f, -0.13501102001039084f, -0.4598775021193313f, 0.8068915093133388f, -0.3326705529509569f}
#define DL_INIT {0.035226291882100656f, -0.08544127388224149f, -0.13501102001039084f, 0.4598775021193313f, 0.8068915093133388f, 0.3326705529509569f}
#define DH_INIT {-0.3326705529509569f, 0.8068915093133388f, -0.4598775021193313f, -0.13501102001039084f, 0.08544127388224149f, 0.035226291882100656f}

// --------------------------------------------------------------------------
// K_MFE: fused q = idwt2(dw3(dwt2(x))) for one 64w x 32h output tile of one
// (b,c) plane.  R6: tile halved vertically (LDS 48.7->27.5 KB, 3->5 blk/CU)
// and x staged de-interleaved (even/odd cols) so the row-DWT reads stride-1
// (kills the 4-way bank conflict seen in R5's counters).
//
// Index algebra (h0 = tile row base; sub row sj <-> global j_g = h0/2-2+sj):
//   subband j_g <- x rows 2*j_g-4 .. 2*j_g+1; x staged from h0-6 ->
//     local x rows of sj = 2sj-2 .. 2sj+3  (sj in [1,20] used)
//   dt row dr = dw3(sub) centered sj=dr+1, taps sub rows dr..dr+2, dr in [1,18]
//   IDWT row i = h0+hl: dt rows (hl>>1)+1+o, coeff D[2o+1-(hl&1)]
// LDS overlays: A = xse/xso[44][40] -> sub[4][21][38] -> lo2/hi2[32][36]
//               B = tlo/thi[44][38] -> dt[4][19][36]      (peak 27.5 KB)
// --------------------------------------------------------------------------
__global__ __launch_bounds__(256) void k_mfe(
    const float* __restrict__ x,
    const float* __restrict__ w1, const float* __restrict__ w5,
    const float* __restrict__ w7, const float* __restrict__ w9,
    float* __restrict__ q, float* __restrict__ nq)
{
  const float RL[6] = RL_INIT, RH[6] = RH_INIT;
  const float DL[6] = DL_INIT, DH[6] = DH_INIT;
  const int bc = blockIdx.z;
  const int c  = bc & 63;
  const int h0 = blockIdx.y * 32, w0 = blockIdx.x * 64;

  __shared__ float A[3520];           // 14.1 KB
  __shared__ float Bm[3344];          // 13.4 KB
  float* xse = A;                     // [44][40] even x cols
  float* xso = A + 1760;              // [44][40] odd  x cols
  float* sub = A;                     // [4][21][38]  (21*38 = 798)
  float* lo2 = A;                     // [32][36]
  float* hi2 = A + 1152;              // [32][36]
  float* tlo = Bm;                    // [44][38]
  float* thi = Bm + 1672;             // [44][38]
  float* dt  = Bm;                    // [4][19][36]  (19*36 = 684)

  float wk[4][9];
#pragma unroll
  for (int i = 0; i < 9; ++i) {
    wk[0][i] = w1[c * 9 + i]; wk[1][i] = w5[c * 9 + i];
    wk[2][i] = w7[c * 9 + i]; wk[3][i] = w9[c * 9 + i];
  }

  // P0: stage x rows [h0-6, h0+37], cols [w0-8, w0+69], zero-pad,
  //     de-interleaved: xse[r][c2] = x[.][2c2], xso[r][c2] = x[.][2c2+1]
  {
    const float* xp = x + (size_t)bc * N_;
    const int xr0 = h0 - 6, xc0 = w0 - 8;
    for (int i = threadIdx.x; i < 44 * 39; i += 256) {
      int r = i / 39, c2 = i % 39;
      int gr = xr0 + r, gc = xc0 + c2 * 2;     // gc even
      float2 v = make_float2(0.f, 0.f);
      if ((unsigned)gr < H_ && (unsigned)gc < W_)
        v = *(const float2*)&xp[gr * W_ + gc];
      xse[r * 40 + c2] = v.x;
      xso[r * 40 + c2] = v.y;
    }
  }
  __syncthreads();

  // P1: row DWT -> tlo/thi [44][37 used]; taps x[2sw+t]:
  //     t even -> xse[sw+t/2], t odd -> xso[sw+(t-1)/2]  (stride-1 reads)
  for (int i = threadIdx.x; i < 44 * 37; i += 256) {
    int r = i / 37, sw = i % 37;
    const float* xe = &xse[r * 40 + sw];
    const float* xo = &xso[r * 40 + sw];
    float e0 = xe[0], o0 = xo[0], e1 = xe[1], o1 = xo[1], e2 = xe[2], o2 = xo[2];
    tlo[r * 38 + sw] = e0*RL[0] + o0*RL[1] + e1*RL[2] + o1*RL[3] + e2*RL[4] + o2*RL[5];
    thi[r * 38 + sw] = e0*RH[0] + o0*RH[1] + e1*RH[2] + o1*RH[3] + e2*RH[4] + o2*RH[5];
  }
  __syncthreads();

  // P2: col DWT -> sub[4][sj][sw], sj in [1,20] (x staged from h0-6 ->
  //     tlo base row = 2sj-2)
  for (int i = threadIdx.x; i < 20 * 37; i += 256) {
    int sj = i / 37 + 1, sw = i % 37;
    int base = (2 * sj - 2) * 38 + sw;
    float ll = 0.f, lh = 0.f, hl = 0.f, hh = 0.f;
#pragma unroll
    for (int t = 0; t < 6; ++t) {
      float a = tlo[base + t * 38];
      float b = thi[base + t * 38];
      ll += a * RL[t]; lh += a * RH[t];
      hl += b * RL[t]; hh += b * RH[t];
    }
    sub[0 * 798 + sj * 38 + sw] = ll;
    sub[1 * 798 + sj * 38 + sw] = lh;
    sub[2 * 798 + sj * 38 + sw] = hl;
    sub[3 * 798 + sj * 38 + sw] = hh;
  }
  __syncthreads();

  // P3: dw3 -> dt[4][dr][dc], dr in [1,18], dc in [1,34];
  //     center (dr+1,dc+1), taps sub rows dr..dr+2, cols dc..dc+2
  for (int i = threadIdx.x; i < 18 * 34; i += 256) {
    int dr = i / 34 + 1, dc = i % 34 + 1;
#pragma unroll
    for (int s = 0; s < 4; ++s) {
      const float* sp = &sub[s * 798 + dr * 38 + dc];
      float acc = 0.f;
#pragma unroll
      for (int dy = 0; dy < 3; ++dy)
#pragma unroll
        for (int dx = 0; dx < 3; ++dx)
          acc += sp[dy * 38 + dx] * wk[s][dy * 3 + dx];
      dt[s * 684 + dr * 36 + dc] = acc;
    }
  }
  __syncthreads();

  // P4: idwt H pass -> lo2/hi2 [32][cols 1..34]
  for (int i = threadIdx.x; i < 32 * 34; i += 256) {
    int hl = i / 34, dc = i % 34 + 1;
    int idx0 = (hl >> 1) + 1;
    int po = hl & 1;
    float lo = 0.f, hi = 0.f;
#pragma unroll
    for (int o = 0; o < 3; ++o) {
      int rr = (idx0 + o) * 36 + dc;
      float cl = DL[2 * o + 1 - po], ch = DH[2 * o + 1 - po];
      lo += dt[0 * 684 + rr] * cl + dt[1 * 684 + rr] * ch;
      hi += dt[2 * 684 + rr] * cl + dt[3 * 684 + rr] * ch;
    }
    lo2[hl * 36 + dc] = lo; hi2[hl * 36 + dc] = hi;
  }
  __syncthreads();

  // P5: idwt W pass -> q + nq
  float nqacc = 0.f;
  for (int i = threadIdx.x; i < 2048; i += 256) {
    int hl = i >> 6, wl = i & 63;
    int ci0 = (wl >> 1) + 1;
    int po = wl & 1;
    const float* lr = &lo2[hl * 36 + ci0];
    const float* hr = &hi2[hl * 36 + ci0];
    float v = 0.f;
#pragma unroll
    for (int o = 0; o < 3; ++o)
      v += lr[o] * DL[2 * o + 1 - po] + hr[o] * DH[2 * o + 1 - po];
    q[(size_t)bc * N_ + (h0 + hl) * W_ + (w0 + wl)] = v;
    nqacc += v * v;
  }
#pragma unroll
  for (int off = 32; off > 0; off >>= 1) nqacc += __shfl_down(nqacc, off, 64);
  __shared__ float red4[4];
  if ((threadIdx.x & 63) == 0) red4[threadIdx.x >> 6] = nqacc;
  __syncthreads();
  if (threadIdx.x == 0)
    atomicAdd(&nq[bc], red4[0] + red4[1] + red4[2] + red4[3]);
}

// --------------------------------------------------------------------------
// K3: conv1x1 half. 128px x 64co tile; 8 px/thread.  (unchanged, validated)
// --------------------------------------------------------------------------
__global__ __launch_bounds__(256) void k_conv1x1(
    const float* __restrict__ x,
    const float* __restrict__ wq,
    const int co_off,
    float* __restrict__ out)
{
  const int b = blockIdx.y;
  const int n0 = blockIdx.x * 128;
  __shared__ float Xs[64][128];
  __shared__ float Wt[64][68];

  for (int i = threadIdx.x; i < 2048; i += 256) {
    int ci = i >> 5, f = i & 31;
    *(float4*)&Xs[ci][f * 4] =
        *(const float4*)&x[((size_t)b * 64 + ci) * N_ + n0 + f * 4];
  }
  for (int i = threadIdx.x; i < 4096; i += 256) {
    int co = i >> 6, ci = i & 63;
    Wt[ci][co] = wq[(co_off + co) * 64 + ci];
  }
  __syncthreads();

  const int px_g = threadIdx.x & 15;
  const int co_g = threadIdx.x >> 4;
  const int p0 = px_g * 4;
  float acc[4][8] = {};
#pragma unroll 2
  for (int ci = 0; ci < 64; ++ci) {
    float4 x0 = *(const float4*)&Xs[ci][p0];
    float4 x1 = *(const float4*)&Xs[ci][64 + p0];
    float4 wv = *(const float4*)&Wt[ci][co_g * 4];
    const float wr[4] = {wv.x, wv.y, wv.z, wv.w};
    const float xr[8] = {x0.x, x0.y, x0.z, x0.w, x1.x, x1.y, x1.z, x1.w};
#pragma unroll
    for (int i = 0; i < 4; ++i)
#pragma unroll
      for (int j = 0; j < 8; ++j)
        acc[i][j] += wr[i] * xr[j];
  }
#pragma unroll
  for (int i = 0; i < 4; ++i) {
    float* op = &out[((size_t)b * 64 + co_g * 4 + i) * N_ + n0];
    *(float4*)&op[p0]      = make_float4(acc[i][0], acc[i][1], acc[i][2], acc[i][3]);
    *(float4*)&op[64 + p0] = make_float4(acc[i][4], acc[i][5], acc[i][6], acc[i][7]);
  }
}

// --------------------------------------------------------------------------
// K4k: dw3 on k-half (LDS halo tile) + S/nk reduction.  (unchanged, validated)
// --------------------------------------------------------------------------
__global__ __launch_bounds__(256) void k_kred(
    const float* __restrict__ kpre,
    const float* __restrict__ q,
    const float* __restrict__ wc,
    float* __restrict__ S,
    float* __restrict__ nk)
{
  const int b = blockIdx.z, hd = blockIdx.y, tile = blockIdx.x;
  const int h0 = (tile >> 3) * 32, w0 = (tile & 7) * 32;
  const int d = threadIdx.x >> 5, lane = threadIdx.x & 31;
  const int ck = hd * 8 + d;

  __shared__ float ks[8][34][36];

  for (int i = threadIdx.x; i < 9248; i += 256) {
    int ch = i / 1156, rem = i % 1156;
    int r = rem / 34, cc = rem % 34;
    int gh = h0 - 1 + r, gw = w0 - 1 + cc;
    float v = 0.f;
    if ((unsigned)gh < H_ && (unsigned)gw < W_)
      v = kpre[((size_t)b * 64 + hd * 8 + ch) * N_ + gh * W_ + gw];
    ks[ch][r][cc] = v;
  }
  __syncthreads();

  float wk[9];
#pragma unroll
  for (int i = 0; i < 9; ++i) wk[i] = wc[ck * 9 + i];
  const float* qp = q + ((size_t)b * 64 + hd * 8) * N_;

  float sacc[8] = {};
  float nkacc = 0.f;
  for (int r = 0; r < 32; ++r) {
    float kv = 0.f;
#pragma unroll
    for (int dy = 0; dy < 3; ++dy)
#pragma unroll
      for (int dx = 0; dx < 3; ++dx)
        kv += ks[d][r + dy][lane + dx] * wk[dy * 3 + dx];
    nkacc += kv * kv;
    const size_t npix = (size_t)(h0 + r) * W_ + w0 + lane;
#pragma unroll
    for (int cc = 0; cc < 8; ++cc)
      sacc[cc] += qp[(size_t)cc * N_ + npix] * kv;
  }
#pragma unroll
  for (int m = 16; m >= 1; m >>= 1) {
#pragma unroll
    for (int cc = 0; cc < 8; ++cc) sacc[cc] += __shfl_xor(sacc[cc], m, 64);
    nkacc += __shfl_xor(nkacc, m, 64);
  }
  if (lane == 0) {
#pragma unroll
    for (int cc = 0; cc < 8; ++cc)
      atomicAdd(&S[(((size_t)b * 8 + hd) * 8 + cc) * 8 + d], sacc[cc]);
    atomicAdd(&nk[((size_t)b * 8 + hd) * 8 + d], nkacc);
  }
}

// --------------------------------------------------------------------------
// K4v: dw3 on v-half, 32x32 LDS-tiled with halo.  (unchanged, validated)
// --------------------------------------------------------------------------
__global__ __launch_bounds__(256) void k_dw3v(
    const float* __restrict__ vpre,
    const float* __restrict__ wc,
    float* __restrict__ v)
{
  const int tile = blockIdx.x, cv = blockIdx.y, b = blockIdx.z;
  const int h0 = (tile >> 3) * 32, w0 = (tile & 7) * 32;
  __shared__ float vs[34][36];

  const float* vp = vpre + ((size_t)b * 64 + cv) * N_;
  for (int i = threadIdx.x; i < 1156; i += 256) {
    int r = i / 34, cc = i % 34;
    int gh = h0 - 1 + r, gw = w0 - 1 + cc;
    float val = 0.f;
    if ((unsigned)gh < H_ && (unsigned)gw < W_) val = vp[gh * W_ + gw];
    vs[r][cc] = val;
  }
  __syncthreads();

  float wk[9];
#pragma unroll
  for (int i = 0; i < 9; ++i) wk[i] = wc[(64 + cv) * 9 + i];

  for (int i = threadIdx.x; i < 1024; i += 256) {
    int r = i >> 5, cc = i & 31;
    float acc = 0.f;
#pragma unroll
    for (int dy = 0; dy < 3; ++dy)
#pragma unroll
      for (int dx = 0; dx < 3; ++dx)
        acc += vs[r + dy][cc + dx] * wk[dy * 3 + dx];
    v[((size_t)b * 64 + cv) * N_ + (h0 + r) * W_ + w0 + cc] = acc;
  }
}

// --------------------------------------------------------------------------
// K6: out = w_proj @ ((A1 v_r) * (A2 v_d)), attention softmaxes recomputed
// per block.  (unchanged, validated)
// --------------------------------------------------------------------------
__global__ __launch_bounds__(256) void k_out(
    const float* __restrict__ vr, const float* __restrict__ vd,
    const float* __restrict__ S1, const float* __restrict__ S2,
    const float* __restrict__ nq, const float* __restrict__ nk1,
    const float* __restrict__ nk2, const float* __restrict__ temp,
    const float* __restrict__ P,
    float* __restrict__ out)
{
  const int b = blockIdx.y;
  const int n0 = blockIdx.x * 64;
  __shared__ float us[64][64];
  __shared__ float Pl[64][68];
  __shared__ float a1s[512], a2s[512];

  for (int i = threadIdx.x; i < 4096; i += 256) {
    int co = i >> 6, cc = i & 63;
    Pl[cc][co] = P[co * 64 + cc];
  }
  if (threadIdx.x < 64) {
    const int t = threadIdx.x;
    const int h = t >> 3;
    const float tp = temp[h];
    const float qn = fmaxf(sqrtf(nq[b * 64 + t]), 1e-12f);
    const size_t rowoff = ((size_t)b * 64 + t) * 8;
    const size_t noff = ((size_t)b * 8 + h) * 8;
    float l[8];
#pragma unroll
    for (int d = 0; d < 8; ++d)
      l[d] = S1[rowoff + d] / (qn * fmaxf(sqrtf(nk1[noff + d]), 1e-12f)) * tp;
    float m = l[0];
#pragma unroll
    for (int d = 1; d < 8; ++d) m = fmaxf(m, l[d]);
    float sum = 0.f;
#pragma unroll
    for (int d = 0; d < 8; ++d) { l[d] = expf(l[d] - m); sum += l[d]; }
#pragma unroll
    for (int d = 0; d < 8; ++d) a1s[t * 8 + d] = l[d] / sum;
#pragma unroll
    for (int d = 0; d < 8; ++d)
      l[d] = S2[rowoff + d] / fmaxf(sqrtf(nk2[noff + d]), 1e-12f) * tp;
    m = l[0];
#pragma unroll
    for (int d = 1; d < 8; ++d) m = fmaxf(m, l[d]);
    sum = 0.f;
#pragma unroll
    for (int d = 0; d < 8; ++d) { l[d] = expf(l[d] - m); sum += l[d]; }
#pragma unroll
    for (int d = 0; d < 8; ++d) a2s[t * 8 + d] = l[d] / sum;
  }
  __syncthreads();

  {
    const int px = threadIdx.x & 63;
    const int g = threadIdx.x >> 6;
    const int ch0 = g * 16;
    float vrr[16], vdd[16];
#pragma unroll
    for (int j = 0; j < 16; ++j) {
      vrr[j] = vr[((size_t)b * 64 + ch0 + j) * N_ + n0 + px];
      vdd[j] = vd[((size_t)b * 64 + ch0 + j) * N_ + n0 + px];
    }
#pragma unroll
    for (int j = 0; j < 16; ++j) {
      const int c = ch0 + j;
      const int base = (j & 8);
      float s = 0.f, t2 = 0.f;
#pragma unroll
      for (int dd = 0; dd < 8; ++dd) {
        s  += a1s[c * 8 + dd] * vrr[base + dd];
        t2 += a2s[c * 8 + dd] * vdd[base + dd];
      }
      us[c][px] = s * t2;
    }
  }
  __syncthreads();

  const int px_g = threadIdx.x & 15;
  const int co_g = threadIdx.x >> 4;
  const int p0 = px_g * 4;
  float acc[4][4] = {};
#pragma unroll 2
  for (int cc = 0; cc < 64; ++cc) {
    float4 uv = *(const float4*)&us[cc][p0];
    float4 pv = *(const float4*)&Pl[cc][co_g * 4];
    const float pr[4] = {pv.x, pv.y, pv.z, pv.w};
    const float ur[4] = {uv.x, uv.y, uv.z, uv.w};
#pragma unroll
    for (int i = 0; i < 4; ++i)
#pragma unroll
      for (int j = 0; j < 4; ++j)
        acc[i][j] += pr[i] * ur[j];
  }
#pragma unroll
  for (int i = 0; i < 4; ++i)
    *(float4*)&out[((size_t)b * 64 + co_g * 4 + i) * N_ + n0 + p0] =
        make_float4(acc[i][0], acc[i][1], acc[i][2], acc[i][3]);
}

// --------------------------------------------------------------------------
extern "C" void kernel_launch(void* const* d_in, const int* in_sizes, int n_in,
                              void* d_out, int out_size, void* d_ws, size_t ws_size,
                              hipStream_t stream) {
  (void)in_sizes; (void)n_in; (void)out_size;
  const float* rgb  = (const float*)d_in[0];
  const float* dep  = (const float*)d_in[1];
  const float* temp = (const float*)d_in[2];
  const float* wqr  = (const float*)d_in[3];
  const float* wqd  = (const float*)d_in[4];
  const float* wqc  = (const float*)d_in[5];
  const float* w1   = (const float*)d_in[6];
  const float* w5   = (const float*)d_in[7];
  const float* w7   = (const float*)d_in[8];
  const float* w9   = (const float*)d_in[9];
  const float* wp   = (const float*)d_in[10];
  float* out = (float*)d_out;

  const size_t WS_NEEDED = 203475968;
  if (ws_size < WS_NEEDED) return;

  char* ws = (char*)d_ws;
  float* q   = (float*)(ws + 0);
  float* v_d = q;                      // q dead after depth k-reduce
  float* v_r = (float*)(ws + 67108864);
  float* big = (float*)(ws + 134217728);   // conv1x1 scratch (67.1 MB)
  char* redb = ws + 203440128;
  float* S1  = (float*)(redb);
  float* S2  = (float*)(redb + 8192);
  float* nq  = (float*)(redb + 16384);
  float* nk1 = (float*)(redb + 17408);
  float* nk2 = (float*)(redb + 18432);

  hipMemsetAsync(redb, 0, 19456, stream);

  // q = mfe(rgb), fully fused (64w x 32h tiles)
  k_mfe<<<dim3(4, 8, 256), 256, 0, stream>>>(rgb, w1, w5, w7, w9, q, nq);

  // rgb stream
  k_conv1x1<<<dim3(512, 4), 256, 0, stream>>>(rgb, wqr, 0, big);
  k_kred<<<dim3(64, 8, 4), 256, 0, stream>>>(big, q, wqc, S1, nk1);
  k_conv1x1<<<dim3(512, 4), 256, 0, stream>>>(rgb, wqr, 64, big);
  k_dw3v<<<dim3(64, 64, 4), 256, 0, stream>>>(big, wqc, v_r);

  // depth stream
  k_conv1x1<<<dim3(512, 4), 256, 0, stream>>>(dep, wqd, 0, big);
  k_kred<<<dim3(64, 8, 4), 256, 0, stream>>>(big, q, wqc, S2, nk2);
  k_conv1x1<<<dim3(512, 4), 256, 0, stream>>>(dep, wqd, 64, big);
  k_dw3v<<<dim3(64, 64, 4), 256, 0, stream>>>(big, wqc, v_d);

  // gated projection with fused attention softmaxes
  k_out<<<dim3(1024, 4), 256, 0, stream>>>(v_r, v_d, S1, S2, nq, nk1, nk2,
                                           temp, wp, out);
}